// Round 9
// baseline (170.763 us; speedup 1.0000x reference)
//
#include <hip/hip_runtime.h>

// GroundTruthBasedPriorNetwork: mus = W2·tanh(W1·gather(gt,parents)+b1)+b2, logvars = 0
// Shapes: gt[B,64] f32, W1[64,16,8], b1[64,16], W2[64,16], b2[64], parent_idx[64,8] i32
// Output: mus [B*64] then logvars [B*64], both f32.
//
// v9b: v9 with the cvt_pkrtz type fix (__fp16-vec result bit_cast through u32
// into the _Float16x8 MFMA fragment; bit patterns identical).
// Design (R0-R7 evidence): wall == 2.07 x aggregate VALU issue-cycles across
// all 8 prior configs => VALU-throughput roofline. Lever: move the matmul to
// the matrix pipe. One mfma_f32_32x32x16_f16 per (node-pair, 32-row tile):
//   M=32 = 2 nodes x 16 hidden  -> A = block-diag W1 (f16, loop-invariant regs)
//   K=16 = 2 nodes x 8 parents  -> zero K-padding (band-DAG block-diagonal)
//   N=32 = batch rows           -> B = gathered x (per-lane contiguous window)
// Safety: (a) k-mapping errors cancel (A,B packed with same slot convention);
// (b) C/D layout col=lane&31, row=(reg&3)+8*(reg>>2)+4*(lane>>5) HW-verified
// [m74/m101]; (c) b1 folded as MFMA C-operand; (d) W2 dot: lanes l and l^32
// hold complementary h-halves of one batch row -> 8 pk_fma + 1 shfl_xor.
// Precision: f16 in, f32 accum: ~+2-3e-3 on the 7.8e-3 Pade absmax; thr 2.73e-2.
// Block mapping: bid = q*256 + tc -> XCD(bid&7)=tc&7: all 8 blocks of one
// row-chunk land on ONE XCD -> gt tile fetched ~once into its L2.

#define BATCH   131072
#define NODES   64
#define HID     16
#define MAXP    8
#define TPB     256
#define NBLOCKS 2048
#define TM      32             // rows per MFMA tile
#define UNITS   16             // tiles per wave (512/32)

typedef float v2     __attribute__((ext_vector_type(2)));
typedef float v4     __attribute__((ext_vector_type(4)));
typedef float f32x16 __attribute__((ext_vector_type(16)));
typedef _Float16 h8v __attribute__((ext_vector_type(8)));
typedef unsigned u32x4 __attribute__((ext_vector_type(4)));

__device__ __forceinline__ v2 tanh2(v2 x) {
    v2 x2  = x * x;
    v2 num = x2 * (x2 + 105.f) + 945.f;          // 945 + 105 x^2 + x^4
    v2 den = x2 * (x2 * 15.f + 420.f) + 945.f;   // 945 + 420 x^2 + 15 x^4
    v2 r;
    r.x = __builtin_amdgcn_rcpf(den.x);
    r.y = __builtin_amdgcn_rcpf(den.y);
    return x * num * r;
}

__device__ __forceinline__ unsigned pk16(float a, float b) {
    return __builtin_bit_cast(unsigned, __builtin_amdgcn_cvt_pkrtz(a, b));
}

__global__ __launch_bounds__(TPB, 4)
void prior_kernel(const float* __restrict__ gt,
                  const float* __restrict__ W1,
                  const float* __restrict__ b1,
                  const float* __restrict__ W2,
                  const float* __restrict__ b2,
                  const int*   __restrict__ parent_idx,
                  float* __restrict__ out)
{
    const int lane = threadIdx.x & 63;
    const int widx = threadIdx.x >> 6;           // wave in block: 0..3
    const int q    = blockIdx.x >> 8;            // pair-quad: 0..7
    const int tc   = blockIdx.x & 255;           // row-chunk; XCD = bid&7 = tc&7
    const int pair = q * 4 + widx;               // node pair: 0..31
    const int n0   = pair * 2, n1 = n0 + 1;
    const int sl   = lane & 31;                  // sub-lane: A-row (m) / B-col (n)
    const int half = lane >> 5;                  // k-block: 0 -> node0, 1 -> node1

    // ---- A-frag: block-diagonal W1 in f16 (loop-invariant) ----
    // Assumed A layout: A[m = lane&31][k = 8*(lane>>5)+j], j=0..7.
    // m<16 -> node0 h=m (nonzero only k<8); m>=16 -> node1 h=m-16 (only k>=8).
    h8v afrag;
    #pragma unroll
    for (int j = 0; j < 8; ++j) {
        float w = 0.f;
        if (!half) { if (sl < 16)  w = W1[(n0 * HID + sl) * MAXP + j]; }
        else       { if (sl >= 16) w = W1[(n1 * HID + (sl - 16)) * MAXP + j]; }
        afrag[j] = (_Float16)w;
    }

    // ---- C-in = b1 (free bias), per-reg W2, via VERIFIED C/D row map ----
    f32x16 cfrag;
    float  w2f[16];
    #pragma unroll
    for (int r = 0; r < 16; ++r) {
        const int m = (r & 3) + 8 * (r >> 2) + 4 * half;   // [m74/m101]
        cfrag[r] = (m < 16) ? b1[n0 * HID + m] : b1[n1 * HID + (m - 16)];
        w2f[r]   = (m < 16) ? W2[n0 * HID + m] : W2[n1 * HID + (m - 16)];
    }
    v2 w2v[8];
    #pragma unroll
    for (int i = 0; i < 8; ++i) { v2 t = { w2f[2 * i], w2f[2 * i + 1] }; w2v[i] = t; }
    const float b2v0 = b2[n0], b2v1 = b2[n1];

    // ---- B gather: lane sl = batch row, window = contiguous parents of its node
    const int nd = half ? n1 : n0;
    const int cs = parent_idx[nd * MAXP];        // first parent; window cs..cs+7
                                                 // (padded slots hit zeroed W1)
    const unsigned rbase   = (unsigned)tc * 512u + (unsigned)sl;
    unsigned       idx     = rbase * 64u + (unsigned)cs;
    const unsigned ISTEP   = (unsigned)TM * 64u;            // 2048 floats / tile
    const unsigned idxLast = idx + (UNITS - 1) * ISTEP;
    unsigned       om      = rbase * 64u + (unsigned)nd;    // this lane stores its node
    const unsigned LV      = (unsigned)BATCH * 64u;

    v4 r0 = *(const v4*)(gt + idx);
    v4 r1 = *(const v4*)(gt + idx + 4);

    #pragma unroll 1
    for (int t = 0; t < UNITS; ++t) {
        // prefetch next tile's window (clamped re-read on last iter)
        unsigned nidx = idx + ISTEP;
        if (nidx > idxLast) nidx = idxLast;
        v4 rn0 = *(const v4*)(gt + nidx);
        v4 rn1 = *(const v4*)(gt + nidx + 4);
        idx = nidx;

        // pack x window to f16 B-frag: B[k = 8*half + j][n = sl]
        u32x4 upk = { pk16(r0.x, r0.y), pk16(r0.z, r0.w),
                      pk16(r1.x, r1.y), pk16(r1.z, r1.w) };
        h8v bfrag = __builtin_bit_cast(h8v, upk);

        // a[m][n] = sum_k W1blk[m][k] * x[k][n] + b1[m]   (bias via C-in)
        f32x16 acc = __builtin_amdgcn_mfma_f32_32x32x16_f16(afrag, bfrag, cfrag, 0, 0, 0);

        // tanh + W2 dot: regs r<8 -> node0's 8 h, r>=8 -> node1's 8 h
        v2 s0 = { 0.f, 0.f }, s1 = { 0.f, 0.f };
        #pragma unroll
        for (int i = 0; i < 4; ++i) {
            v2 a = { acc[2 * i], acc[2 * i + 1] };
            s0 = __builtin_elementwise_fma(tanh2(a), w2v[i], s0);
        }
        #pragma unroll
        for (int i = 4; i < 8; ++i) {
            v2 a = { acc[2 * i], acc[2 * i + 1] };
            s1 = __builtin_elementwise_fma(tanh2(a), w2v[i], s1);
        }
        // lanes l and l^32 hold complementary h-halves of the same batch row
        float S0 = s0.x + s0.y;  S0 += __shfl_xor(S0, 32, 64);
        float S1 = s1.x + s1.y;  S1 += __shfl_xor(S1, 32, 64);
        const float mu = half ? (S1 + b2v1) : (S0 + b2v0);

        out[om]      = mu;        // mus[row = rbase + t*32][node nd]
        out[om + LV] = 0.f;       // logvars = 0
        om += ISTEP;
        r0 = rn0; r1 = rn1;
    }
}

extern "C" void kernel_launch(void* const* d_in, const int* in_sizes, int n_in,
                              void* d_out, int out_size, void* d_ws, size_t ws_size,
                              hipStream_t stream)
{
    const float* gt  = (const float*)d_in[0];
    const float* W1  = (const float*)d_in[1];
    const float* b1  = (const float*)d_in[2];
    const float* W2  = (const float*)d_in[3];
    const float* b2  = (const float*)d_in[4];
    const int*   pix = (const int*)d_in[5];
    float* out = (float*)d_out;

    prior_kernel<<<NBLOCKS, TPB, 0, stream>>>(gt, W1, b1, W2, b2, pix, out);
}